// Round 3
// baseline (327.178 us; speedup 1.0000x reference)
//
#include <hip/hip_runtime.h>
#include <math.h>

// order-preserving float -> uint key (ascending float => ascending uint)
__device__ inline unsigned fkey(float f) {
  unsigned bits = __float_as_uint(f);
  return (bits & 0x80000000u) ? ~bits : (bits | 0x80000000u);
}

// ---------------------------------------------------------------------------
// Kernel 1 (new): split-K fp64 GEMM. Grid (N/128, 2). Block 256 thr.
// Tile 128 tokens x 64 experts; thread 8 tok x 4 exp; DC=32; K-half = D/2.
// Partial sums rounded to fp32 into p0/p1 (row-major [token][64]).
// ---------------------------------------------------------------------------
__global__ __launch_bounds__(256, 2) void logits_split_kernel(
    const float* __restrict__ x, const float* __restrict__ W,
    float* __restrict__ p0, float* __restrict__ p1, int N, int D) {
  __shared__ __attribute__((aligned(16))) float xs[32][132];
  __shared__ __attribute__((aligned(16))) float wsm[32][68];
  const int tid = threadIdx.x;
  const int tok0 = blockIdx.x * 128;
  const int kh = blockIdx.y;
  const int Dh = D >> 1;
  const int k0 = kh * Dh;
  const int tg = tid & 15;   // token group: tokens tg*8 .. +7
  const int eg = tid >> 4;   // expert group: experts eg*4 .. +3

  double acc[8][4];
#pragma unroll
  for (int i = 0; i < 8; ++i)
#pragma unroll
    for (int j = 0; j < 4; ++j) acc[i][j] = 0.0;

  for (int kc = k0; kc < k0 + Dh; kc += 32) {
    // stage x: 128 rows x 8 float4 = 1024 slots, 4/thread
#pragma unroll
    for (int it = 0; it < 4; ++it) {
      int idx = it * 256 + tid;
      int row = idx >> 3;            // 0..127
      int c4 = idx & 7;
      float4 v = *(const float4*)(x + (size_t)(tok0 + row) * D + kc + c4 * 4);
      float a[4] = {v.x, v.y, v.z, v.w};
#pragma unroll
      for (int jj = 0; jj < 4; ++jj) {
        int j = (jj + tid) & 3;
        float e = (j == 0) ? a[0] : (j == 1) ? a[1] : (j == 2) ? a[2] : a[3];
        xs[c4 * 4 + j][row] = e;
      }
    }
    // stage W: 64 rows x 8 float4 = 512 slots, 2/thread
#pragma unroll
    for (int it = 0; it < 2; ++it) {
      int idx = it * 256 + tid;
      int row = idx >> 3;            // 0..63
      int c4 = idx & 7;
      float4 v = *(const float4*)(W + (size_t)row * D + kc + c4 * 4);
      float a[4] = {v.x, v.y, v.z, v.w};
#pragma unroll
      for (int jj = 0; jj < 4; ++jj) {
        int j = (jj + tid) & 3;
        float e = (j == 0) ? a[0] : (j == 1) ? a[1] : (j == 2) ? a[2] : a[3];
        wsm[c4 * 4 + j][row] = e;
      }
    }
    __syncthreads();

#pragma unroll 2
    for (int kk = 0; kk < 32; ++kk) {
      float4 xlo = *(const float4*)&xs[kk][tg * 8];
      float4 xhi = *(const float4*)&xs[kk][tg * 8 + 4];
      float4 wv = *(const float4*)&wsm[kk][eg * 4];
      double xd[8] = {(double)xlo.x, (double)xlo.y, (double)xlo.z, (double)xlo.w,
                      (double)xhi.x, (double)xhi.y, (double)xhi.z, (double)xhi.w};
      double wd[4] = {(double)wv.x, (double)wv.y, (double)wv.z, (double)wv.w};
#pragma unroll
      for (int i = 0; i < 8; ++i)
#pragma unroll
        for (int j = 0; j < 4; ++j)
          acc[i][j] = fma(xd[i], wd[j], acc[i][j]);
    }
    __syncthreads();
  }

  float* dst = (kh == 0 ? p0 : p1) + (size_t)tok0 * 64;
#pragma unroll
  for (int i = 0; i < 8; ++i) {
    float4 o = {(float)acc[i][0], (float)acc[i][1],
                (float)acc[i][2], (float)acc[i][3]};
    *(float4*)(dst + (size_t)(tg * 8 + i) * 64 + eg * 4) = o;
  }
}

// ---------------------------------------------------------------------------
// Kernel 1b: combine halves + bias (fp64 adds), write logits + logitsT.
// Block = 64-token tile, 256 threads.
// ---------------------------------------------------------------------------
__global__ __launch_bounds__(256) void combine_kernel(
    const float* __restrict__ p0, const float* __restrict__ p1,
    const float* __restrict__ b, float* __restrict__ logits,
    float* __restrict__ logitsT, int N) {
  __shared__ float ls[64][68];
  const int tid = threadIdx.x;
  const int tok0 = blockIdx.x * 64;

  // 64 tok x 16 float4 = 1024 slots, 4/thread
#pragma unroll
  for (int it = 0; it < 4; ++it) {
    int idx = it * 256 + tid;
    int row = idx >> 4;   // 0..63
    int c4 = idx & 15;
    size_t off = (size_t)(tok0 + row) * 64 + c4 * 4;
    float4 a = *(const float4*)(p0 + off);
    float4 c = *(const float4*)(p1 + off);
    ls[row][c4 * 4 + 0] = (float)((double)a.x + (double)c.x + (double)b[c4 * 4 + 0]);
    ls[row][c4 * 4 + 1] = (float)((double)a.y + (double)c.y + (double)b[c4 * 4 + 1]);
    ls[row][c4 * 4 + 2] = (float)((double)a.z + (double)c.z + (double)b[c4 * 4 + 2]);
    ls[row][c4 * 4 + 3] = (float)((double)a.w + (double)c.w + (double)b[c4 * 4 + 3]);
  }
  __syncthreads();
  // row-major out
#pragma unroll
  for (int it = 0; it < 4; ++it) {
    int idx = it * 256 + tid;
    int row = idx >> 4, c4 = idx & 15;
    float4 v = {ls[row][c4 * 4], ls[row][c4 * 4 + 1],
                ls[row][c4 * 4 + 2], ls[row][c4 * 4 + 3]};
    *(float4*)(logits + (size_t)(tok0 + row) * 64 + c4 * 4) = v;
  }
  // transposed out: 64 experts x 16 float4(tokens), 4/thread
#pragma unroll
  for (int it = 0; it < 4; ++it) {
    int idx = it * 256 + tid;
    int e = idx >> 4, t4 = idx & 15;
    float4 v = {ls[t4 * 4][e], ls[t4 * 4 + 1][e], ls[t4 * 4 + 2][e],
                ls[t4 * 4 + 3][e]};
    *(float4*)(logitsT + (size_t)e * N + tok0 + t4 * 4) = v;
  }
}

// ---------------------------------------------------------------------------
// Kernel 1 (fallback, round-2 proven): single-kernel fp64 GEMM -> both layouts
// ---------------------------------------------------------------------------
__global__ __launch_bounds__(256) void logits_kernel_fb(
    const float* __restrict__ x, const float* __restrict__ W,
    const float* __restrict__ b, float* __restrict__ logits,
    float* __restrict__ logitsT, int N, int D) {
  const int DC = 128;
  __shared__ __attribute__((aligned(16))) float xs[128][68];
  __shared__ __attribute__((aligned(16))) float wsm[128][68];
  const int tid = threadIdx.x;
  const int tok0 = blockIdx.x * 64;
  const int tr = tid & 15;
  const int tc = tid >> 4;
  double acc[4][4];
#pragma unroll
  for (int i = 0; i < 4; ++i)
#pragma unroll
    for (int j = 0; j < 4; ++j) acc[i][j] = 0.0;
  for (int kc = 0; kc < D; kc += DC) {
#pragma unroll
    for (int it = 0; it < 8; ++it) {
      int idx4 = it * 256 + tid;
      int row = idx4 >> 5;
      int c4 = idx4 & 31;
      float4 xv = *(const float4*)(x + (size_t)(tok0 + row) * D + kc + c4 * 4);
      float4 wv = *(const float4*)(W + (size_t)row * D + kc + c4 * 4);
      float xa[4] = {xv.x, xv.y, xv.z, xv.w};
      float wa[4] = {wv.x, wv.y, wv.z, wv.w};
#pragma unroll
      for (int jj = 0; jj < 4; ++jj) {
        int j = (jj + tid) & 3;
        float xe = (j == 0) ? xa[0] : (j == 1) ? xa[1] : (j == 2) ? xa[2] : xa[3];
        float we = (j == 0) ? wa[0] : (j == 1) ? wa[1] : (j == 2) ? wa[2] : wa[3];
        xs[c4 * 4 + j][row] = xe;
        wsm[c4 * 4 + j][row] = we;
      }
    }
    __syncthreads();
#pragma unroll 4
    for (int kk = 0; kk < DC; ++kk) {
      float4 xv = *(const float4*)&xs[kk][tr * 4];
      float4 wv = *(const float4*)&wsm[kk][tc * 4];
      const float xa[4] = {xv.x, xv.y, xv.z, xv.w};
      const float wa[4] = {wv.x, wv.y, wv.z, wv.w};
#pragma unroll
      for (int i = 0; i < 4; ++i) {
        double xd = (double)xa[i];
#pragma unroll
        for (int j = 0; j < 4; ++j)
          acc[i][j] = fma(xd, (double)wa[j], acc[i][j]);
      }
    }
    __syncthreads();
  }
  double bb[4] = {(double)b[tc * 4 + 0], (double)b[tc * 4 + 1],
                  (double)b[tc * 4 + 2], (double)b[tc * 4 + 3]};
  float f[4][4];
#pragma unroll
  for (int i = 0; i < 4; ++i)
#pragma unroll
    for (int j = 0; j < 4; ++j) f[i][j] = (float)(acc[i][j] + bb[j]);
#pragma unroll
  for (int i = 0; i < 4; ++i) {
    float4 o = {f[i][0], f[i][1], f[i][2], f[i][3]};
    *(float4*)(logits + (size_t)(tok0 + tr * 4 + i) * 64 + tc * 4) = o;
  }
#pragma unroll
  for (int j = 0; j < 4; ++j) {
    float4 o = {f[0][j], f[1][j], f[2][j], f[3][j]};
    *(float4*)(logitsT + (size_t)(tc * 4 + j) * N + tok0 + tr * 4) = o;
  }
}

// ---------------------------------------------------------------------------
// Kernel 2: per-expert k-th-largest via 2-bit-digit bisection (16 passes).
// No atomics: per-thread compare counts, packed u64 wave+block reduction.
// KPT4>0: keys register-resident (KPT4 float4 per thread, block=1024 thr).
// ---------------------------------------------------------------------------
template <int KPT4>
__global__ __launch_bounds__(1024) void select_kernel(
    const float* __restrict__ logitsT, unsigned* __restrict__ ukeys,
    int N, int k) {
  __shared__ unsigned long long part[16];
  __shared__ unsigned s_cur;
  const int e = blockIdx.x;
  const int tid = threadIdx.x;
  const int wid = tid >> 6;
  const int lane = tid & 63;

  const float4* src = (const float4*)(logitsT + (size_t)e * N);
  unsigned key[KPT4 > 0 ? KPT4 * 4 : 4];
  if (KPT4 > 0) {
#pragma unroll
    for (int i = 0; i < (KPT4 > 0 ? KPT4 : 1); ++i) {
      float4 v = src[tid + i * 1024];
      key[i * 4 + 0] = fkey(v.x);
      key[i * 4 + 1] = fkey(v.y);
      key[i * 4 + 2] = fkey(v.z);
      key[i * 4 + 3] = fkey(v.w);
    }
  }

  unsigned cur = 0;
  for (int s = 30; s >= 0; s -= 2) {
    unsigned c1 = cur | (1u << s);
    unsigned c2 = cur | (2u << s);
    unsigned c3 = cur | (3u << s);
    unsigned n1 = 0, n2 = 0, n3 = 0;
    if (KPT4 > 0) {
#pragma unroll
      for (int i = 0; i < (KPT4 > 0 ? KPT4 * 4 : 1); ++i) {
        unsigned u = key[i];
        n1 += (u >= c1) ? 1u : 0u;
        n2 += (u >= c2) ? 1u : 0u;
        n3 += (u >= c3) ? 1u : 0u;
      }
    } else {
      for (int i = tid; i < (N >> 2); i += 1024) {
        float4 v = src[i];
        unsigned u0 = fkey(v.x), u1 = fkey(v.y), u2 = fkey(v.z), u3 = fkey(v.w);
        n1 += (u0 >= c1) + (u1 >= c1) + (u2 >= c1) + (u3 >= c1);
        n2 += (u0 >= c2) + (u1 >= c2) + (u2 >= c2) + (u3 >= c2);
        n3 += (u0 >= c3) + (u1 >= c3) + (u2 >= c3) + (u3 >= c3);
      }
    }
    unsigned long long pk = (unsigned long long)n1 |
                            ((unsigned long long)n2 << 21) |
                            ((unsigned long long)n3 << 42);
#pragma unroll
    for (int off = 32; off; off >>= 1) pk += __shfl_xor(pk, off);
    if (lane == 0) part[wid] = pk;
    __syncthreads();
    if (tid == 0) {
      unsigned long long t = 0;
#pragma unroll
      for (int w = 0; w < 16; ++w) t += part[w];
      unsigned m1 = (unsigned)(t & 0x1FFFFFu);
      unsigned m2 = (unsigned)((t >> 21) & 0x1FFFFFu);
      unsigned m3 = (unsigned)(t >> 42);
      unsigned kk = (unsigned)k;
      unsigned nxt = cur;
      if (m3 >= kk) nxt = c3;
      else if (m2 >= kk) nxt = c2;
      else if (m1 >= kk) nxt = c1;
      s_cur = nxt;
    }
    __syncthreads();
    cur = s_cur;
  }
  if (tid == 0) ukeys[e] = cur;
}

__global__ void init_counts(float* counts) { counts[threadIdx.x] = 0.0f; }

// ---------------------------------------------------------------------------
// Kernel 3: one wave per token; lane = expert; candidate iff key >= ukeys[e].
// ---------------------------------------------------------------------------
__global__ __launch_bounds__(256) void assign_kernel(
    const float* __restrict__ logits, const unsigned* __restrict__ ukeys,
    float* __restrict__ out, float* __restrict__ counts, int N) {
  const int lane = threadIdx.x & 63;
  const int token = blockIdx.x * 4 + (threadIdx.x >> 6);

  float v = logits[(size_t)token * 64 + lane];
  unsigned u = fkey(v);
  bool cand = (u >= ukeys[lane]);
  float cv = cand ? v : -INFINITY;
  float m = cv;
#pragma unroll
  for (int off = 32; off; off >>= 1) m = fmaxf(m, __shfl_xor(m, off));
  unsigned long long mask = __ballot(cand && (v == m));
  bool sel = (mask != 0ull);
  int minexp = sel ? (__ffsll((long long)mask) - 1) : -1;

  if (lane == 0) {
    out[token] = sel ? m : 0.0f;
    out[N + token] = (float)minexp;
    out[2 * N + token] = sel ? 1.0f : 0.0f;
  }
  if (sel && lane == minexp) atomicAdd(&counts[lane], 1.0f);
}

// ---------------------------------------------------------------------------
// Kernel 4: load-balance loss (E=64), fp64.
// ---------------------------------------------------------------------------
__global__ void loss_kernel(const float* __restrict__ counts,
                            float* __restrict__ out, int N) {
  if (threadIdx.x == 0) {
    double s = 0.0;
    for (int e = 0; e < 64; ++e) s += (double)counts[e];
    double mean = s / 64.0;
    double l = 0.0;
    for (int e = 0; e < 64; ++e) {
      double d = (double)counts[e] - mean;
      l += d * d;
    }
    l = (l / 64.0) / (mean + 1e-9);
    out[3 * (size_t)N] = (float)l;
  }
}

extern "C" void kernel_launch(void* const* d_in, const int* in_sizes, int n_in,
                              void* d_out, int out_size, void* d_ws, size_t ws_size,
                              hipStream_t stream) {
  const float* x = (const float*)d_in[0];
  const float* W = (const float*)d_in[1];
  const float* b = (const float*)d_in[2];

  const int E = in_sizes[2];      // 64
  const int D = in_sizes[1] / E;  // 1024
  const int N = in_sizes[0] / D;  // 32768

  int k = (int)((double)N / (double)(E > 1 ? E : 1) * 1.2);
  if (k < 1) k = 1;
  if (k > N) k = N;               // 614

  const size_t NE = (size_t)N * E;
  float* out = (float*)d_out;

  const size_t need_split = NE * 4 * sizeof(float) + 1024;
  const bool can_split =
      (ws_size >= need_split) && (E == 64) && (N % 128 == 0) && (D % 64 == 0);

  if (can_split) {
    float* p0 = (float*)d_ws;
    float* p1 = p0 + NE;
    float* logits = p1 + NE;
    float* logitsT = logits + NE;
    unsigned* ukeys = (unsigned*)(logitsT + NE);
    float* counts = (float*)(ukeys + 64);

    dim3 grid(N / 128, 2);
    logits_split_kernel<<<grid, 256, 0, stream>>>(x, W, p0, p1, N, D);
    combine_kernel<<<N / 64, 256, 0, stream>>>(p0, p1, b, logits, logitsT, N);
    if (N == 32768)
      select_kernel<8><<<64, 1024, 0, stream>>>(logitsT, ukeys, N, k);
    else
      select_kernel<0><<<64, 1024, 0, stream>>>(logitsT, ukeys, N, k);
    init_counts<<<1, 64, 0, stream>>>(counts);
    assign_kernel<<<N / 4, 256, 0, stream>>>(logits, ukeys, out, counts, N);
    loss_kernel<<<1, 64, 0, stream>>>(counts, out, N);
  } else {
    float* logits = (float*)d_ws;
    float* logitsT = logits + NE;
    unsigned* ukeys = (unsigned*)(logitsT + NE);
    float* counts = (float*)(ukeys + 64);

    logits_kernel_fb<<<N / 64, 256, 0, stream>>>(x, W, b, logits, logitsT, N, D);
    if (N == 32768)
      select_kernel<8><<<64, 1024, 0, stream>>>(logitsT, ukeys, N, k);
    else
      select_kernel<0><<<64, 1024, 0, stream>>>(logitsT, ukeys, N, k);
    init_counts<<<1, 64, 0, stream>>>(counts);
    assign_kernel<<<N / 4, 256, 0, stream>>>(logits, ukeys, out, counts, N);
    loss_kernel<<<1, 64, 0, stream>>>(counts, out, N);
  }
}

// Round 5
// 152.926 us; speedup vs baseline: 2.1395x; 2.1395x over previous
//
#include <hip/hip_runtime.h>
#include <math.h>

typedef __attribute__((ext_vector_type(4))) double d4;

// order-preserving float -> uint key (ascending float => ascending uint)
__device__ inline unsigned fkey(float f) {
  unsigned bits = __float_as_uint(f);
  return (bits & 0x80000000u) ? ~bits : (bits | 0x80000000u);
}

// ---------------------------------------------------------------------------
// Kernel 0: f64-MFMA layout probe. 1 wave. Stages known integer matrices
// with the ASSUMED A/B layouts (A: lane->A[l&15][l>>4]; B: lane->B[l>>4][l&15]),
// runs one v_mfma_f64_16x16x4_f64, and tests the accumulator against the true
// product under 4 candidate D mappings. flag = first matching mapping, else 4.
// Exact-integer values => exact fp64 arithmetic => bitwise comparison valid.
// ---------------------------------------------------------------------------
__global__ void probe_kernel(unsigned* __restrict__ flag) {
  __shared__ double A[16][4];
  __shared__ double B[4][16];
  const int l = threadIdx.x;        // 64 threads = 1 wave
  {
    int i = l & 15, kk = l >> 4;
    A[i][kk] = (double)(i * 4 + kk + 1);
    B[kk][i] = (double)(i * 7 + kk * 3 + 2);
  }
  __syncthreads();
  const int l15 = l & 15, lk = l >> 4;
  double a = A[l15][lk];
  double b = B[lk][l15];
  d4 acc = (d4)0.0;
  acc = __builtin_amdgcn_mfma_f64_16x16x4f64(a, b, acc, 0, 0, 0);

  unsigned res = 4;
  for (int m = 3; m >= 0; --m) {
    bool ok = true;
#pragma unroll
    for (int i = 0; i < 4; ++i) {
      int tr_ = (m < 2) ? ((m == 0) ? 4 * lk + i : lk + 4 * i) : l15;
      int tc_ = (m < 2) ? l15 : ((m == 2) ? 4 * lk + i : lk + 4 * i);
      double ref = 0.0;
#pragma unroll
      for (int kk = 0; kk < 4; ++kk) ref += A[tr_][kk] * B[kk][tc_];
      ok = ok && (acc[i] == ref);
    }
    if (__all(ok)) res = (unsigned)m;
  }
  if (l == 0) flag[0] = res;
}

// ---------------------------------------------------------------------------
// Kernel 1a: logits = x @ W^T + b via v_mfma_f64_16x16x4_f64 (full fp64 acc).
// Runs only if probe found a valid D mapping (flag < 4).
// Tile 64 tok x 64 exp per 256-thr block (4 waves); wave w owns rows w*16..+15.
// DC=64 K-chunk staged fp32 in LDS, converted to fp64 at fragment read.
// Epilogue writes through LDS using the probed D mapping.
// ---------------------------------------------------------------------------
__global__ __launch_bounds__(256) void logits_mfma_kernel(
    const float* __restrict__ x, const float* __restrict__ W,
    const float* __restrict__ bias, float* __restrict__ logits,
    float* __restrict__ logitsT, const unsigned* __restrict__ flag,
    int N, int D) {
  const unsigned fl = flag[0];
  if (fl >= 4u) return;   // layout unknown -> VALU kernel handles it

  __shared__ __attribute__((aligned(16))) float xs[64 * 76];
  __shared__ __attribute__((aligned(16))) float wsm[64 * 76];

  const int tid = threadIdx.x;
  const int tok0 = blockIdx.x * 64;
  const int w = tid >> 6;      // wave 0..3
  const int l = tid & 63;      // lane
  const int l15 = l & 15;
  const int lk = l >> 4;       // k-group 0..3

  d4 acc[4];
#pragma unroll
  for (int ct = 0; ct < 4; ++ct) acc[ct] = (d4)0.0;

  const int xb = (w * 16 + l15) * 76 + lk;  // + s*4 per K-step
  const int wb = l15 * 76 + lk;             // + ct*16*76 + s*4

  for (int kc = 0; kc < D; kc += 64) {
#pragma unroll
    for (int it = 0; it < 4; ++it) {
      int slot = it * 256 + tid;           // 0..1023
      int row = slot >> 4;                 // 0..63
      int c4 = slot & 15;                  // float4 col
      float4 xv = *(const float4*)(x + (size_t)(tok0 + row) * D + kc + c4 * 4);
      float4 wv = *(const float4*)(W + (size_t)row * D + kc + c4 * 4);
      *(float4*)(xs + row * 76 + c4 * 4) = xv;
      *(float4*)(wsm + row * 76 + c4 * 4) = wv;
    }
    __syncthreads();

#pragma unroll
    for (int s = 0; s < 16; ++s) {
      double a = (double)xs[xb + s * 4];
      double b0 = (double)wsm[wb + 0 * 1216 + s * 4];
      double b1 = (double)wsm[wb + 1 * 1216 + s * 4];
      double b2 = (double)wsm[wb + 2 * 1216 + s * 4];
      double b3 = (double)wsm[wb + 3 * 1216 + s * 4];
      acc[0] = __builtin_amdgcn_mfma_f64_16x16x4f64(a, b0, acc[0], 0, 0, 0);
      acc[1] = __builtin_amdgcn_mfma_f64_16x16x4f64(a, b1, acc[1], 0, 0, 0);
      acc[2] = __builtin_amdgcn_mfma_f64_16x16x4f64(a, b2, acc[2], 0, 0, 0);
      acc[3] = __builtin_amdgcn_mfma_f64_16x16x4f64(a, b3, acc[3], 0, 0, 0);
    }
    __syncthreads();
  }

  // ---- epilogue: probed D mapping, bias add (fp64), LDS round-trip ----
  float* ls = xs;  // 64 x 68 fp32 view; last loop iter ended in __syncthreads
#pragma unroll
  for (int ct = 0; ct < 4; ++ct) {
#pragma unroll
    for (int i = 0; i < 4; ++i) {
      int tr_, tc_;
      if (fl < 2u) { tc_ = l15; tr_ = (fl == 0u) ? 4 * lk + i : lk + 4 * i; }
      else         { tr_ = l15; tc_ = (fl == 2u) ? 4 * lk + i : lk + 4 * i; }
      int col = ct * 16 + tc_;
      ls[(w * 16 + tr_) * 68 + col] = (float)(acc[ct][i] + (double)bias[col]);
    }
  }
  __syncthreads();
  // row-major stores
#pragma unroll
  for (int it = 0; it < 4; ++it) {
    int slot = it * 256 + tid;
    int row = slot >> 4, c4 = slot & 15;
    float4 v = {ls[row * 68 + c4 * 4 + 0], ls[row * 68 + c4 * 4 + 1],
                ls[row * 68 + c4 * 4 + 2], ls[row * 68 + c4 * 4 + 3]};
    *(float4*)(logits + (size_t)(tok0 + row) * 64 + c4 * 4) = v;
  }
  // transposed stores
#pragma unroll
  for (int it = 0; it < 4; ++it) {
    int slot = it * 256 + tid;
    int e = slot >> 4, t4 = slot & 15;
    float4 v = {ls[(t4 * 4 + 0) * 68 + e], ls[(t4 * 4 + 1) * 68 + e],
                ls[(t4 * 4 + 2) * 68 + e], ls[(t4 * 4 + 3) * 68 + e]};
    *(float4*)(logitsT + (size_t)e * N + tok0 + t4 * 4) = v;
  }
}

// ---------------------------------------------------------------------------
// Kernel 1b: VALU fp64 fallback (round-2 proven). Runs only if flag == 4.
// ---------------------------------------------------------------------------
__global__ __launch_bounds__(256) void logits_valu_kernel(
    const float* __restrict__ x, const float* __restrict__ W,
    const float* __restrict__ b, float* __restrict__ logits,
    float* __restrict__ logitsT, const unsigned* __restrict__ flag,
    int N, int D) {
  if (flag[0] < 4u) return;   // MFMA kernel already did the work

  const int DC = 128;
  __shared__ __attribute__((aligned(16))) float xs[128][68];
  __shared__ __attribute__((aligned(16))) float wsm[128][68];
  const int tid = threadIdx.x;
  const int tok0 = blockIdx.x * 64;
  const int tr = tid & 15;
  const int tc = tid >> 4;
  double acc[4][4];
#pragma unroll
  for (int i = 0; i < 4; ++i)
#pragma unroll
    for (int j = 0; j < 4; ++j) acc[i][j] = 0.0;
  for (int kc = 0; kc < D; kc += DC) {
#pragma unroll
    for (int it = 0; it < 8; ++it) {
      int idx4 = it * 256 + tid;
      int row = idx4 >> 5;
      int c4 = idx4 & 31;
      float4 xv = *(const float4*)(x + (size_t)(tok0 + row) * D + kc + c4 * 4);
      float4 wv = *(const float4*)(W + (size_t)row * D + kc + c4 * 4);
      float xa[4] = {xv.x, xv.y, xv.z, xv.w};
      float wa[4] = {wv.x, wv.y, wv.z, wv.w};
#pragma unroll
      for (int jj = 0; jj < 4; ++jj) {
        int j = (jj + tid) & 3;
        float xe = (j == 0) ? xa[0] : (j == 1) ? xa[1] : (j == 2) ? xa[2] : xa[3];
        float we = (j == 0) ? wa[0] : (j == 1) ? wa[1] : (j == 2) ? wa[2] : wa[3];
        xs[c4 * 4 + j][row] = xe;
        wsm[c4 * 4 + j][row] = we;
      }
    }
    __syncthreads();
#pragma unroll 4
    for (int kk = 0; kk < DC; ++kk) {
      float4 xv = *(const float4*)&xs[kk][tr * 4];
      float4 wv = *(const float4*)&wsm[kk][tc * 4];
      const float xa[4] = {xv.x, xv.y, xv.z, xv.w};
      const float wa[4] = {wv.x, wv.y, wv.z, wv.w};
#pragma unroll
      for (int i = 0; i < 4; ++i) {
        double xd = (double)xa[i];
#pragma unroll
        for (int j = 0; j < 4; ++j)
          acc[i][j] = fma(xd, (double)wa[j], acc[i][j]);
      }
    }
    __syncthreads();
  }
  double bb[4] = {(double)b[tc * 4 + 0], (double)b[tc * 4 + 1],
                  (double)b[tc * 4 + 2], (double)b[tc * 4 + 3]};
  float f[4][4];
#pragma unroll
  for (int i = 0; i < 4; ++i)
#pragma unroll
    for (int j = 0; j < 4; ++j) f[i][j] = (float)(acc[i][j] + bb[j]);
#pragma unroll
  for (int i = 0; i < 4; ++i) {
    float4 o = {f[i][0], f[i][1], f[i][2], f[i][3]};
    *(float4*)(logits + (size_t)(tok0 + tr * 4 + i) * 64 + tc * 4) = o;
  }
#pragma unroll
  for (int j = 0; j < 4; ++j) {
    float4 o = {f[0][j], f[1][j], f[2][j], f[3][j]};
    *(float4*)(logitsT + (size_t)(tc * 4 + j) * N + tok0 + tr * 4) = o;
  }
}

// ---------------------------------------------------------------------------
// Kernel 2: per-expert k-th-largest via 2-bit-digit bisection (16 passes).
// No atomics: per-thread compare counts, packed u64 wave+block reduction.
// ---------------------------------------------------------------------------
template <int KPT4>
__global__ __launch_bounds__(1024) void select_kernel(
    const float* __restrict__ logitsT, unsigned* __restrict__ ukeys,
    int N, int k) {
  __shared__ unsigned long long part[16];
  __shared__ unsigned s_cur;
  const int e = blockIdx.x;
  const int tid = threadIdx.x;
  const int wid = tid >> 6;
  const int lane = tid & 63;

  const float4* src = (const float4*)(logitsT + (size_t)e * N);
  unsigned key[KPT4 > 0 ? KPT4 * 4 : 4];
  if (KPT4 > 0) {
#pragma unroll
    for (int i = 0; i < (KPT4 > 0 ? KPT4 : 1); ++i) {
      float4 v = src[tid + i * 1024];
      key[i * 4 + 0] = fkey(v.x);
      key[i * 4 + 1] = fkey(v.y);
      key[i * 4 + 2] = fkey(v.z);
      key[i * 4 + 3] = fkey(v.w);
    }
  }

  unsigned cur = 0;
  for (int s = 30; s >= 0; s -= 2) {
    unsigned c1 = cur | (1u << s);
    unsigned c2 = cur | (2u << s);
    unsigned c3 = cur | (3u << s);
    unsigned n1 = 0, n2 = 0, n3 = 0;
    if (KPT4 > 0) {
#pragma unroll
      for (int i = 0; i < (KPT4 > 0 ? KPT4 * 4 : 1); ++i) {
        unsigned u = key[i];
        n1 += (u >= c1) ? 1u : 0u;
        n2 += (u >= c2) ? 1u : 0u;
        n3 += (u >= c3) ? 1u : 0u;
      }
    } else {
      for (int i = tid; i < (N >> 2); i += 1024) {
        float4 v = src[i];
        unsigned u0 = fkey(v.x), u1 = fkey(v.y), u2 = fkey(v.z), u3 = fkey(v.w);
        n1 += (u0 >= c1) + (u1 >= c1) + (u2 >= c1) + (u3 >= c1);
        n2 += (u0 >= c2) + (u1 >= c2) + (u2 >= c2) + (u3 >= c2);
        n3 += (u0 >= c3) + (u1 >= c3) + (u2 >= c3) + (u3 >= c3);
      }
    }
    unsigned long long pk = (unsigned long long)n1 |
                            ((unsigned long long)n2 << 21) |
                            ((unsigned long long)n3 << 42);
#pragma unroll
    for (int off = 32; off; off >>= 1) pk += __shfl_xor(pk, off);
    if (lane == 0) part[wid] = pk;
    __syncthreads();
    if (tid == 0) {
      unsigned long long t = 0;
#pragma unroll
      for (int w = 0; w < 16; ++w) t += part[w];
      unsigned m1 = (unsigned)(t & 0x1FFFFFu);
      unsigned m2 = (unsigned)((t >> 21) & 0x1FFFFFu);
      unsigned m3 = (unsigned)(t >> 42);
      unsigned kk = (unsigned)k;
      unsigned nxt = cur;
      if (m3 >= kk) nxt = c3;
      else if (m2 >= kk) nxt = c2;
      else if (m1 >= kk) nxt = c1;
      s_cur = nxt;
    }
    __syncthreads();
    cur = s_cur;
  }
  if (tid == 0) ukeys[e] = cur;
}

// ---------------------------------------------------------------------------
// Kernel 3: one wave per token; lane = expert; candidate iff key >= ukeys[e].
// NO global atomics (counts derived later from assigned_expert).
// ---------------------------------------------------------------------------
__global__ __launch_bounds__(256) void assign_kernel(
    const float* __restrict__ logits, const unsigned* __restrict__ ukeys,
    float* __restrict__ out, int N) {
  const int lane = threadIdx.x & 63;
  const int token = blockIdx.x * 4 + (threadIdx.x >> 6);

  float v = logits[(size_t)token * 64 + lane];
  unsigned u = fkey(v);
  bool cand = (u >= ukeys[lane]);
  float cv = cand ? v : -INFINITY;
  float m = cv;
#pragma unroll
  for (int off = 32; off; off >>= 1) m = fmaxf(m, __shfl_xor(m, off));
  unsigned long long mask = __ballot(cand && (v == m));
  bool sel = (mask != 0ull);
  int minexp = sel ? (__ffsll((long long)mask) - 1) : -1;

  if (lane == 0) {
    out[token] = sel ? m : 0.0f;
    out[N + token] = (float)minexp;
    out[2 * N + token] = sel ? 1.0f : 0.0f;
  }
}

// ---------------------------------------------------------------------------
// Kernel 4: counts (LDS histogram, single block) + load-balance loss, fused.
// ---------------------------------------------------------------------------
__global__ __launch_bounds__(1024) void count_loss_kernel(
    const float* __restrict__ assigned, float* __restrict__ out, int N) {
  __shared__ unsigned hist[16][64];
  const int tid = threadIdx.x;
  const int wid = tid >> 6;
  hist[tid >> 6][tid & 63] = 0u;   // 1024 == 16*64
  __syncthreads();
  for (int i = tid; i < N; i += 1024) {
    int e = (int)assigned[i];
    if (e >= 0) atomicAdd(&hist[wid][e], 1u);
  }
  __syncthreads();
  if (tid < 64) {
    unsigned c = 0;
#pragma unroll
    for (int w = 0; w < 16; ++w) c += hist[w][tid];
    double cd = (double)c;
    double s = cd;
#pragma unroll
    for (int off = 32; off; off >>= 1) s += __shfl_xor(s, off);
    double mean = s / 64.0;
    double d = cd - mean;
    d = d * d;
#pragma unroll
    for (int off = 32; off; off >>= 1) d += __shfl_xor(d, off);
    if (tid == 0) out[3 * (size_t)N] = (float)((d / 64.0) / (mean + 1e-9));
  }
}

extern "C" void kernel_launch(void* const* d_in, const int* in_sizes, int n_in,
                              void* d_out, int out_size, void* d_ws, size_t ws_size,
                              hipStream_t stream) {
  const float* x = (const float*)d_in[0];
  const float* W = (const float*)d_in[1];
  const float* b = (const float*)d_in[2];

  const int E = in_sizes[2];      // 64
  const int D = in_sizes[1] / E;  // 1024
  const int N = in_sizes[0] / D;  // 32768

  int k = (int)((double)N / (double)(E > 1 ? E : 1) * 1.2);
  if (k < 1) k = 1;
  if (k > N) k = N;               // 614

  const size_t NE = (size_t)N * E;
  float* out = (float*)d_out;

  float* logits = (float*)d_ws;        // N*E fp32 (8 MB)
  float* logitsT = logits + NE;        // N*E fp32 (8 MB)
  unsigned* ukeys = (unsigned*)(logitsT + NE);
  unsigned* flag = ukeys + 64;

  probe_kernel<<<1, 64, 0, stream>>>(flag);
  logits_mfma_kernel<<<N / 64, 256, 0, stream>>>(x, W, b, logits, logitsT,
                                                 flag, N, D);
  logits_valu_kernel<<<N / 64, 256, 0, stream>>>(x, W, b, logits, logitsT,
                                                 flag, N, D);
  if (N == 32768)
    select_kernel<8><<<64, 1024, 0, stream>>>(logitsT, ukeys, N, k);
  else
    select_kernel<0><<<64, 1024, 0, stream>>>(logitsT, ukeys, N, k);
  assign_kernel<<<N / 4, 256, 0, stream>>>(logits, ukeys, out, N);
  count_loss_kernel<<<1, 1024, 0, stream>>>(out + N, out, N);
}

// Round 6
// 143.526 us; speedup vs baseline: 2.2796x; 1.0655x over previous
//
#include <hip/hip_runtime.h>
#include <math.h>

typedef __attribute__((ext_vector_type(4))) double d4;

// order-preserving float -> uint key (ascending float => ascending uint)
__device__ inline unsigned fkey(float f) {
  unsigned bits = __float_as_uint(f);
  return (bits & 0x80000000u) ? ~bits : (bits | 0x80000000u);
}

// ---------------------------------------------------------------------------
// Kernel 0: f64-MFMA layout probe (round-5 proven). flag<4 = D mapping id.
// ---------------------------------------------------------------------------
__global__ void probe_kernel(unsigned* __restrict__ flag) {
  __shared__ double A[16][4];
  __shared__ double B[4][16];
  const int l = threadIdx.x;
  {
    int i = l & 15, kk = l >> 4;
    A[i][kk] = (double)(i * 4 + kk + 1);
    B[kk][i] = (double)(i * 7 + kk * 3 + 2);
  }
  __syncthreads();
  const int l15 = l & 15, lk = l >> 4;
  double a = A[l15][lk];
  double b = B[lk][l15];
  d4 acc = (d4)0.0;
  acc = __builtin_amdgcn_mfma_f64_16x16x4f64(a, b, acc, 0, 0, 0);

  unsigned res = 4;
  for (int m = 3; m >= 0; --m) {
    bool ok = true;
#pragma unroll
    for (int i = 0; i < 4; ++i) {
      int tr_ = (m < 2) ? ((m == 0) ? 4 * lk + i : lk + 4 * i) : l15;
      int tc_ = (m < 2) ? l15 : ((m == 2) ? 4 * lk + i : lk + 4 * i);
      double ref = 0.0;
#pragma unroll
      for (int kk = 0; kk < 4; ++kk) ref += A[tr_][kk] * B[kk][tc_];
      ok = ok && (acc[i] == ref);
    }
    if (__all(ok)) res = (unsigned)m;
  }
  if (l == 0) flag[0] = res;
}

// ---------------------------------------------------------------------------
// Kernel 1a: logits = x @ W^T + b via v_mfma_f64_16x16x4_f64.
// 512 thr = 8 waves; wave w: rows (w&3)*16, cols (w>>2)*32 (2 acc tiles).
// DC=64 K-chunks; tiles staged in LDS as fp64 (cvt once at staging);
// register-prefetch double buffering hides global latency under MFMA.
// Accumulation order identical to round-5 kernel -> bitwise-same logits.
// ---------------------------------------------------------------------------
__global__ __launch_bounds__(512, 4) void logits_mfma_kernel(
    const float* __restrict__ x, const float* __restrict__ W,
    const float* __restrict__ bias, float* __restrict__ logits,
    float* __restrict__ logitsT, const unsigned* __restrict__ flag,
    int N, int D) {
  const unsigned fl = flag[0];
  if (fl >= 4u) return;   // layout unknown -> VALU kernel handles it

  __shared__ __attribute__((aligned(16))) double xs64[64 * 66];
  __shared__ __attribute__((aligned(16))) double ws64[64 * 66];

  const int tid = threadIdx.x;
  const int tok0 = blockIdx.x * 64;
  const int w = tid >> 6;        // wave 0..7
  const int l = tid & 63;
  const int l15 = l & 15;
  const int lk = l >> 4;
  const int rb = (w & 3) * 16;   // row base
  const int cb = (w >> 2) * 32;  // col base

  d4 acc[2];
  acc[0] = (d4)0.0;
  acc[1] = (d4)0.0;

  // staging slots: thread -> (row r0 / r0+32, float4-col c40)
  const int r0 = tid >> 4;       // 0..31
  const int c40 = tid & 15;

  float4 rx0, rx1, rw0, rw1;
  rx0 = *(const float4*)(x + (size_t)(tok0 + r0) * D + c40 * 4);
  rx1 = *(const float4*)(x + (size_t)(tok0 + 32 + r0) * D + c40 * 4);
  rw0 = *(const float4*)(W + (size_t)r0 * D + c40 * 4);
  rw1 = *(const float4*)(W + (size_t)(32 + r0) * D + c40 * 4);

  const int nch = D >> 6;
  const int xa0 = (rb + l15) * 66 + lk;
  const int ba0 = (cb + l15) * 66 + lk;

  for (int c = 0; c < nch; ++c) {
    // ---- write prefetched chunk to LDS (fp32 -> fp64, exact) ----
    {
      double* d0 = xs64 + r0 * 66 + c40 * 4;
      *(double2*)(d0) = make_double2((double)rx0.x, (double)rx0.y);
      *(double2*)(d0 + 2) = make_double2((double)rx0.z, (double)rx0.w);
      double* d1 = xs64 + (32 + r0) * 66 + c40 * 4;
      *(double2*)(d1) = make_double2((double)rx1.x, (double)rx1.y);
      *(double2*)(d1 + 2) = make_double2((double)rx1.z, (double)rx1.w);
      double* e0 = ws64 + r0 * 66 + c40 * 4;
      *(double2*)(e0) = make_double2((double)rw0.x, (double)rw0.y);
      *(double2*)(e0 + 2) = make_double2((double)rw0.z, (double)rw0.w);
      double* e1 = ws64 + (32 + r0) * 66 + c40 * 4;
      *(double2*)(e1) = make_double2((double)rw1.x, (double)rw1.y);
      *(double2*)(e1 + 2) = make_double2((double)rw1.z, (double)rw1.w);
    }
    __syncthreads();
    // ---- issue next chunk's global loads (hidden under MFMA phase) ----
    if (c + 1 < nch) {
      int kc = (c + 1) << 6;
      rx0 = *(const float4*)(x + (size_t)(tok0 + r0) * D + kc + c40 * 4);
      rx1 = *(const float4*)(x + (size_t)(tok0 + 32 + r0) * D + kc + c40 * 4);
      rw0 = *(const float4*)(W + (size_t)r0 * D + kc + c40 * 4);
      rw1 = *(const float4*)(W + (size_t)(32 + r0) * D + kc + c40 * 4);
    }
    // ---- MFMA phase: 16 K-steps of 4 ----
#pragma unroll
    for (int s = 0; s < 16; ++s) {
      double a = xs64[xa0 + 4 * s];
      double b0 = ws64[ba0 + 4 * s];
      double b1 = ws64[ba0 + 16 * 66 + 4 * s];
      acc[0] = __builtin_amdgcn_mfma_f64_16x16x4f64(a, b0, acc[0], 0, 0, 0);
      acc[1] = __builtin_amdgcn_mfma_f64_16x16x4f64(a, b1, acc[1], 0, 0, 0);
    }
    __syncthreads();
  }

  // ---- epilogue: probed D mapping, bias add (fp64), LDS round-trip ----
  float* ls = (float*)xs64;  // 64 x 68 fp32 view; loop ended in __syncthreads
#pragma unroll
  for (int ct = 0; ct < 2; ++ct) {
#pragma unroll
    for (int i = 0; i < 4; ++i) {
      int tr_, tc_;
      if (fl < 2u) { tc_ = l15; tr_ = (fl == 0u) ? 4 * lk + i : lk + 4 * i; }
      else         { tr_ = l15; tc_ = (fl == 2u) ? 4 * lk + i : lk + 4 * i; }
      int col = cb + ct * 16 + tc_;
      ls[(rb + tr_) * 68 + col] = (float)(acc[ct][i] + (double)bias[col]);
    }
  }
  __syncthreads();
  // row-major stores (1024 slots, 2/thread)
#pragma unroll
  for (int it = 0; it < 2; ++it) {
    int slot = it * 512 + tid;
    int row = slot >> 4, c4 = slot & 15;
    float4 v = {ls[row * 68 + c4 * 4 + 0], ls[row * 68 + c4 * 4 + 1],
                ls[row * 68 + c4 * 4 + 2], ls[row * 68 + c4 * 4 + 3]};
    *(float4*)(logits + (size_t)(tok0 + row) * 64 + c4 * 4) = v;
  }
  // transposed stores
#pragma unroll
  for (int it = 0; it < 2; ++it) {
    int slot = it * 512 + tid;
    int e = slot >> 4, t4 = slot & 15;
    float4 v = {ls[(t4 * 4 + 0) * 68 + e], ls[(t4 * 4 + 1) * 68 + e],
                ls[(t4 * 4 + 2) * 68 + e], ls[(t4 * 4 + 3) * 68 + e]};
    *(float4*)(logitsT + (size_t)e * N + tok0 + t4 * 4) = v;
  }
}

// ---------------------------------------------------------------------------
// Kernel 1b: VALU fp64 fallback (round-2 proven). Runs only if flag == 4.
// ---------------------------------------------------------------------------
__global__ __launch_bounds__(256) void logits_valu_kernel(
    const float* __restrict__ x, const float* __restrict__ W,
    const float* __restrict__ b, float* __restrict__ logits,
    float* __restrict__ logitsT, const unsigned* __restrict__ flag,
    int N, int D) {
  if (flag[0] < 4u) return;

  const int DC = 128;
  __shared__ __attribute__((aligned(16))) float xs[128][68];
  __shared__ __attribute__((aligned(16))) float wsm[128][68];
  const int tid = threadIdx.x;
  const int tok0 = blockIdx.x * 64;
  const int tr = tid & 15;
  const int tc = tid >> 4;
  double acc[4][4];
#pragma unroll
  for (int i = 0; i < 4; ++i)
#pragma unroll
    for (int j = 0; j < 4; ++j) acc[i][j] = 0.0;
  for (int kc = 0; kc < D; kc += DC) {
#pragma unroll
    for (int it = 0; it < 8; ++it) {
      int idx4 = it * 256 + tid;
      int row = idx4 >> 5;
      int c4 = idx4 & 31;
      float4 xv = *(const float4*)(x + (size_t)(tok0 + row) * D + kc + c4 * 4);
      float4 wv = *(const float4*)(W + (size_t)row * D + kc + c4 * 4);
      float xa[4] = {xv.x, xv.y, xv.z, xv.w};
      float wa[4] = {wv.x, wv.y, wv.z, wv.w};
#pragma unroll
      for (int jj = 0; jj < 4; ++jj) {
        int j = (jj + tid) & 3;
        float xe = (j == 0) ? xa[0] : (j == 1) ? xa[1] : (j == 2) ? xa[2] : xa[3];
        float we = (j == 0) ? wa[0] : (j == 1) ? wa[1] : (j == 2) ? wa[2] : wa[3];
        xs[c4 * 4 + j][row] = xe;
        wsm[c4 * 4 + j][row] = we;
      }
    }
    __syncthreads();
#pragma unroll 4
    for (int kk = 0; kk < DC; ++kk) {
      float4 xv = *(const float4*)&xs[kk][tr * 4];
      float4 wv = *(const float4*)&wsm[kk][tc * 4];
      const float xa[4] = {xv.x, xv.y, xv.z, xv.w};
      const float wa[4] = {wv.x, wv.y, wv.z, wv.w};
#pragma unroll
      for (int i = 0; i < 4; ++i) {
        double xd = (double)xa[i];
#pragma unroll
        for (int j = 0; j < 4; ++j)
          acc[i][j] = fma(xd, (double)wa[j], acc[i][j]);
      }
    }
    __syncthreads();
  }
  double bb[4] = {(double)b[tc * 4 + 0], (double)b[tc * 4 + 1],
                  (double)b[tc * 4 + 2], (double)b[tc * 4 + 3]};
  float f[4][4];
#pragma unroll
  for (int i = 0; i < 4; ++i)
#pragma unroll
    for (int j = 0; j < 4; ++j) f[i][j] = (float)(acc[i][j] + bb[j]);
#pragma unroll
  for (int i = 0; i < 4; ++i) {
    float4 o = {f[i][0], f[i][1], f[i][2], f[i][3]};
    *(float4*)(logits + (size_t)(tok0 + tr * 4 + i) * 64 + tc * 4) = o;
  }
#pragma unroll
  for (int j = 0; j < 4; ++j) {
    float4 o = {f[0][j], f[1][j], f[2][j], f[3][j]};
    *(float4*)(logitsT + (size_t)(tc * 4 + j) * N + tok0 + tr * 4) = o;
  }
}

// ---------------------------------------------------------------------------
// Kernel 2: per-expert k-th-largest via 2-bit-digit bisection (16 passes).
// ---------------------------------------------------------------------------
template <int KPT4>
__global__ __launch_bounds__(1024) void select_kernel(
    const float* __restrict__ logitsT, unsigned* __restrict__ ukeys,
    int N, int k) {
  __shared__ unsigned long long part[16];
  __shared__ unsigned s_cur;
  const int e = blockIdx.x;
  const int tid = threadIdx.x;
  const int wid = tid >> 6;
  const int lane = tid & 63;

  const float4* src = (const float4*)(logitsT + (size_t)e * N);
  unsigned key[KPT4 > 0 ? KPT4 * 4 : 4];
  if (KPT4 > 0) {
#pragma unroll
    for (int i = 0; i < (KPT4 > 0 ? KPT4 : 1); ++i) {
      float4 v = src[tid + i * 1024];
      key[i * 4 + 0] = fkey(v.x);
      key[i * 4 + 1] = fkey(v.y);
      key[i * 4 + 2] = fkey(v.z);
      key[i * 4 + 3] = fkey(v.w);
    }
  }

  unsigned cur = 0;
  for (int s = 30; s >= 0; s -= 2) {
    unsigned c1 = cur | (1u << s);
    unsigned c2 = cur | (2u << s);
    unsigned c3 = cur | (3u << s);
    unsigned n1 = 0, n2 = 0, n3 = 0;
    if (KPT4 > 0) {
#pragma unroll
      for (int i = 0; i < (KPT4 > 0 ? KPT4 * 4 : 1); ++i) {
        unsigned u = key[i];
        n1 += (u >= c1) ? 1u : 0u;
        n2 += (u >= c2) ? 1u : 0u;
        n3 += (u >= c3) ? 1u : 0u;
      }
    } else {
      for (int i = tid; i < (N >> 2); i += 1024) {
        float4 v = src[i];
        unsigned u0 = fkey(v.x), u1 = fkey(v.y), u2 = fkey(v.z), u3 = fkey(v.w);
        n1 += (u0 >= c1) + (u1 >= c1) + (u2 >= c1) + (u3 >= c1);
        n2 += (u0 >= c2) + (u1 >= c2) + (u2 >= c2) + (u3 >= c2);
        n3 += (u0 >= c3) + (u1 >= c3) + (u2 >= c3) + (u3 >= c3);
      }
    }
    unsigned long long pk = (unsigned long long)n1 |
                            ((unsigned long long)n2 << 21) |
                            ((unsigned long long)n3 << 42);
#pragma unroll
    for (int off = 32; off; off >>= 1) pk += __shfl_xor(pk, off);
    if (lane == 0) part[wid] = pk;
    __syncthreads();
    if (tid == 0) {
      unsigned long long t = 0;
#pragma unroll
      for (int w = 0; w < 16; ++w) t += part[w];
      unsigned m1 = (unsigned)(t & 0x1FFFFFu);
      unsigned m2 = (unsigned)((t >> 21) & 0x1FFFFFu);
      unsigned m3 = (unsigned)(t >> 42);
      unsigned kk = (unsigned)k;
      unsigned nxt = cur;
      if (m3 >= kk) nxt = c3;
      else if (m2 >= kk) nxt = c2;
      else if (m1 >= kk) nxt = c1;
      s_cur = nxt;
    }
    __syncthreads();
    cur = s_cur;
  }
  if (tid == 0) ukeys[e] = cur;
}

// ---------------------------------------------------------------------------
// Kernel 3: one wave per token; lane = expert; candidate iff key >= ukeys[e].
// ---------------------------------------------------------------------------
__global__ __launch_bounds__(256) void assign_kernel(
    const float* __restrict__ logits, const unsigned* __restrict__ ukeys,
    float* __restrict__ out, int N) {
  const int lane = threadIdx.x & 63;
  const int token = blockIdx.x * 4 + (threadIdx.x >> 6);

  float v = logits[(size_t)token * 64 + lane];
  unsigned u = fkey(v);
  bool cand = (u >= ukeys[lane]);
  float cv = cand ? v : -INFINITY;
  float m = cv;
#pragma unroll
  for (int off = 32; off; off >>= 1) m = fmaxf(m, __shfl_xor(m, off));
  unsigned long long mask = __ballot(cand && (v == m));
  bool sel = (mask != 0ull);
  int minexp = sel ? (__ffsll((long long)mask) - 1) : -1;

  if (lane == 0) {
    out[token] = sel ? m : 0.0f;
    out[N + token] = (float)minexp;
    out[2 * N + token] = sel ? 1.0f : 0.0f;
  }
}

// ---------------------------------------------------------------------------
// Kernel 4: counts (LDS histogram, single block) + load-balance loss, fused.
// ---------------------------------------------------------------------------
__global__ __launch_bounds__(1024) void count_loss_kernel(
    const float* __restrict__ assigned, float* __restrict__ out, int N) {
  __shared__ unsigned hist[16][64];
  const int tid = threadIdx.x;
  const int wid = tid >> 6;
  hist[tid >> 6][tid & 63] = 0u;
  __syncthreads();
  for (int i = tid; i < N; i += 1024) {
    int e = (int)assigned[i];
    if (e >= 0) atomicAdd(&hist[wid][e], 1u);
  }
  __syncthreads();
  if (tid < 64) {
    unsigned c = 0;
#pragma unroll
    for (int w = 0; w < 16; ++w) c += hist[w][tid];
    double cd = (double)c;
    double s = cd;
#pragma unroll
    for (int off = 32; off; off >>= 1) s += __shfl_xor(s, off);
    double mean = s / 64.0;
    double d = cd - mean;
    d = d * d;
#pragma unroll
    for (int off = 32; off; off >>= 1) d += __shfl_xor(d, off);
    if (tid == 0) out[3 * (size_t)N] = (float)((d / 64.0) / (mean + 1e-9));
  }
}

extern "C" void kernel_launch(void* const* d_in, const int* in_sizes, int n_in,
                              void* d_out, int out_size, void* d_ws, size_t ws_size,
                              hipStream_t stream) {
  const float* x = (const float*)d_in[0];
  const float* W = (const float*)d_in[1];
  const float* b = (const float*)d_in[2];

  const int E = in_sizes[2];      // 64
  const int D = in_sizes[1] / E;  // 1024
  const int N = in_sizes[0] / D;  // 32768

  int k = (int)((double)N / (double)(E > 1 ? E : 1) * 1.2);
  if (k < 1) k = 1;
  if (k > N) k = N;               // 614

  const size_t NE = (size_t)N * E;
  float* out = (float*)d_out;

  float* logits = (float*)d_ws;        // N*E fp32 (8 MB)
  float* logitsT = logits + NE;        // N*E fp32 (8 MB)
  unsigned* ukeys = (unsigned*)(logitsT + NE);
  unsigned* flag = ukeys + 64;

  probe_kernel<<<1, 64, 0, stream>>>(flag);
  logits_mfma_kernel<<<N / 64, 512, 0, stream>>>(x, W, b, logits, logitsT,
                                                 flag, N, D);
  logits_valu_kernel<<<N / 64, 256, 0, stream>>>(x, W, b, logits, logitsT,
                                                 flag, N, D);
  if (N == 32768)
    select_kernel<8><<<64, 1024, 0, stream>>>(logitsT, ukeys, N, k);
  else
    select_kernel<0><<<64, 1024, 0, stream>>>(logitsT, ukeys, N, k);
  assign_kernel<<<N / 4, 256, 0, stream>>>(logits, ukeys, out, N);
  count_loss_kernel<<<1, 1024, 0, stream>>>(out + N, out, N);
}